// Round 6
// baseline (573.808 us; speedup 1.0000x reference)
//
#include <hip/hip_runtime.h>

#define LOG2E 1.44269504088896340736f
#define QSCALE 0.18033688011112042f  // 0.125 * LOG2E

typedef __attribute__((ext_vector_type(8))) short bf16x8;
typedef __attribute__((ext_vector_type(4))) float f32x4;

__device__ __forceinline__ unsigned short f2b(float f) {
  union { float f; unsigned int u; } x; x.f = f;
  return (unsigned short)((x.u + 0x8000u) >> 16);
}

// pack two fp32 -> two bf16 in 3 VALU ops
__device__ __forceinline__ unsigned int pk_bf16(float a, float b) {
  union { float f; unsigned int u; } xa, xb; xa.f = a; xb.f = b;
  return __builtin_amdgcn_perm(xb.u + 0x8000u, xa.u + 0x8000u, 0x07060302);
}

__device__ __forceinline__ void gld_lds16(const void* g, void* l) {
  __builtin_amdgcn_global_load_lds((const __attribute__((address_space(1))) void*)g,
                                   (__attribute__((address_space(3))) void*)l,
                                   16, 0, 0);
}

// raw workgroup barrier (NO implicit vmcnt drain, unlike __syncthreads)
__device__ __forceinline__ void wgbar() {
  asm volatile("" ::: "memory");
  __builtin_amdgcn_s_barrier();
  asm volatile("" ::: "memory");
}
#define SWAIT(s) asm volatile("s_waitcnt " s ::: "memory")
#define FENCE    asm volatile("" ::: "memory")

// ---------------- fused cast x,y fp32 -> bf16 ----------------
__global__ __launch_bounds__(256) void cast_xy(const float* __restrict__ x,
                                               const float* __restrict__ y,
                                               unsigned short* __restrict__ xb,
                                               unsigned short* __restrict__ yb) {
  int i = blockIdx.x * 256 + threadIdx.x;
  const float* in = x; unsigned short* out = xb;
  if (i >= 2097152) { in = y; out = yb; i -= 2097152; }
  float4 v = ((const float4*)in)[i];
  uint2 o;
  o.x = pk_bf16(v.x, v.y);
  o.y = pk_bf16(v.z, v.w);
  ((uint2*)out)[i] = o;
}

// ---------------- fused transpose+cast of Wkv, Wq, Wo ----------------
__global__ __launch_bounds__(256) void transpose_cast_all(
    const float* __restrict__ Wkv, const float* __restrict__ Wq,
    const float* __restrict__ Wo, unsigned short* __restrict__ wkvt,
    unsigned short* __restrict__ wqt, unsigned short* __restrict__ wot) {
  __shared__ float t[32][33];
  int tb = blockIdx.x;
  const float* W; unsigned short* Wt; int N;
  if (tb < 2048)      { W = Wkv; Wt = wkvt; N = 2048; }
  else if (tb < 3072) { W = Wq;  Wt = wqt;  N = 1024; tb -= 2048; }
  else                { W = Wo;  Wt = wot;  N = 1024; tb -= 3072; }
  const int K = 1024;
  int tilesN = N >> 5;
  int nb = (tb % tilesN) * 32, kb = (tb / tilesN) * 32;
  int j = threadIdx.x & 31, i0 = threadIdx.x >> 5;
  #pragma unroll
  for (int p = 0; p < 4; ++p) {
    int i = i0 + p * 8;
    t[i][j] = W[(size_t)(kb + i) * N + nb + j];
  }
  __syncthreads();
  #pragma unroll
  for (int p = 0; p < 4; ++p) {
    int i = i0 + p * 8;
    Wt[(size_t)(nb + i) * K + kb + j] = f2b(t[j][i]);
  }
}

// ---------------- GEMM: C(MxN) = A(MxK) @ Bt(NxK)^T + bias ----------------
// XOR-granule-swizzled LDS (conflict-free b128 fragment reads).
// MODE 0: fp32 C out. MODE 1: kv -> K[b,h,s,64] + Vt[b,h,64,s]. MODE 2: q -> Q * QSCALE.
template <int MODE>
__global__ __launch_bounds__(256)
void gemm128(const unsigned short* __restrict__ A,
             const unsigned short* __restrict__ Bt,
             const float* __restrict__ bias,
             void* __restrict__ out0, void* __restrict__ out1,
             int M, int N, int K) {
  __shared__ __align__(16) unsigned short As[128 * 64];
  __shared__ __align__(16) unsigned short Bs[128 * 64];
  const int tid = threadIdx.x;
  const int bn = blockIdx.x, bm = blockIdx.y;
  const int wave = tid >> 6, lane = tid & 63;
  const int wm = (wave >> 1) * 64, wn = (wave & 1) * 64;
  const int lrow = lane & 15, quad = lane >> 4;
  const int sw = lrow & 7;  // fragment-read granule swizzle

  f32x4 acc[4][4];
  #pragma unroll
  for (int i = 0; i < 4; ++i)
    #pragma unroll
    for (int j = 0; j < 4; ++j)
      #pragma unroll
      for (int r = 0; r < 4; ++r) acc[i][j][r] = 0.f;

  const unsigned short* Ab = A + (size_t)(bm * 128) * K;
  const unsigned short* Bb = Bt + (size_t)(bn * 128) * K;

  for (int k0 = 0; k0 < K; k0 += 64) {
    #pragma unroll
    for (int i = 0; i < 4; ++i) {
      int e = i * 256 + tid;
      int row = e >> 3, gs = (e & 7) ^ (row & 7);
      gld_lds16(Ab + (size_t)row * K + k0 + gs * 8, &As[e * 8]);
    }
    #pragma unroll
    for (int i = 0; i < 4; ++i) {
      int e = i * 256 + tid;
      int row = e >> 3, gs = (e & 7) ^ (row & 7);
      gld_lds16(Bb + (size_t)row * K + k0 + gs * 8, &Bs[e * 8]);
    }
    __builtin_amdgcn_s_waitcnt(0);
    __syncthreads();
    #pragma unroll
    for (int ks = 0; ks < 2; ++ks) {
      bf16x8 af[4], bf[4];
      const int g = ((ks * 4 + quad) ^ sw) * 8;
      #pragma unroll
      for (int i = 0; i < 4; ++i)
        af[i] = *(const bf16x8*)&As[(wm + i * 16 + lrow) * 64 + g];
      #pragma unroll
      for (int j = 0; j < 4; ++j)
        bf[j] = *(const bf16x8*)&Bs[(wn + j * 16 + lrow) * 64 + g];
      #pragma unroll
      for (int i = 0; i < 4; ++i)
        #pragma unroll
        for (int j = 0; j < 4; ++j)
          acc[i][j] = __builtin_amdgcn_mfma_f32_16x16x32_bf16(af[i], bf[j], acc[i][j], 0, 0, 0);
    }
    __syncthreads();
  }

  const int col0 = bn * 128 + wn;
  #pragma unroll
  for (int i = 0; i < 4; ++i) {
    const int row0 = bm * 128 + wm + i * 16 + quad * 4;
    const int b = row0 >> 11, s0 = row0 & 2047;
    #pragma unroll
    for (int j = 0; j < 4; ++j) {
      const int cc = j * 16 + lrow;
      const float bv = bias[col0 + cc];
      float v0 = acc[i][j][0] + bv, v1 = acc[i][j][1] + bv;
      float v2 = acc[i][j][2] + bv, v3 = acc[i][j][3] + bv;
      if (MODE == 0) {
        float* C = (float*)out0;
        size_t off = (size_t)row0 * N + col0 + cc;
        C[off] = v0; C[off + N] = v1; C[off + 2 * N] = v2; C[off + 3 * N] = v3;
      } else if (MODE == 1) {
        const int h = col0 >> 7;
        if ((col0 & 64) == 0) {  // K half: K[b,h,s,64]
          unsigned short* Kb = (unsigned short*)out0;
          size_t base = ((size_t)(b * 16 + h) * 2048 + s0) * 64 + cc;
          Kb[base] = f2b(v0); Kb[base + 64] = f2b(v1);
          Kb[base + 128] = f2b(v2); Kb[base + 192] = f2b(v3);
        } else {                 // V half: Vt[b,h,64,s]
          unsigned short* Vt = (unsigned short*)out1;
          size_t base = ((size_t)(b * 16 + h) * 64 + cc) * 2048 + s0;
          uint2 p; p.x = pk_bf16(v0, v1); p.y = pk_bf16(v2, v3);
          *(uint2*)&Vt[base] = p;
        }
      } else {  // MODE 2: Q[b,h,s,64] pre-scaled
        v0 *= QSCALE; v1 *= QSCALE; v2 *= QSCALE; v3 *= QSCALE;
        const int h = col0 >> 6;
        unsigned short* Qb = (unsigned short*)out0;
        size_t base = ((size_t)(b * 16 + h) * 2048 + s0) * 64 + cc;
        Qb[base] = f2b(v0); Qb[base + 64] = f2b(v1);
        Qb[base + 128] = f2b(v2); Qb[base + 192] = f2b(v3);
      }
    }
  }
}

// ---------------- flash attention v9: max-occupancy (32 waves/CU) -----------
// 512 threads = 8 waves x 16 q-rows; KVBLK=32 (64 tiles); K,V double-buffered.
// LDS 24576 B -> 4 blocks/CU (grid-limited) = 32 waves/CU, VGPR cap 64.
// One barrier/tile; each wave issues exactly ONE gld_lds per tile (waves 0-3
// stage K, 4-7 stage V) -> per-wave vmcnt discipline: at tile top outstanding
// = [stage(t):1, mask(t):2] -> SWAIT vmcnt(2) retires only the full-tile-old
// stage. Mask loads sit before the SWAIT/barrier fences (cannot sink). P goes
// through a swizzled wave-private 1KB LDS slab (lgkmcnt only, no barrier).

#define ATTN_TILE(T, C)                                                        \
  {                                                                            \
    const int ktn = ((T) + 1) & 63; /* wrapped dummy prefetch at T=63 */       \
    const float* mr = mp + (size_t)lrow * 2048 + (T) * 32 + quad * 4;          \
    f32x4 zl0 = *(const f32x4*)(mr);                                           \
    f32x4 zl1 = *(const f32x4*)(mr + 16);                                      \
    SWAIT("vmcnt(2)"); /* retire stage(T); keep mask(T) in flight */           \
    wgbar();           /* publish K(T),V(T); alt buffers reader-free */        \
    gld_lds16(sptr + (size_t)ktn * sstep, (C) ? sdst0 : sdst1);                \
    const unsigned short* Kc = &Ks[(C)][0];                                    \
    const unsigned short* Vc = &Vs[(C)][0];                                    \
    bf16x8 kf00 = *(const bf16x8*)&Kc[lrow * 64 + ((quad ^ sw7) * 8)];         \
    bf16x8 kf01 = *(const bf16x8*)&Kc[lrow * 64 + (((4 + quad) ^ sw7) * 8)];   \
    bf16x8 kf10 = *(const bf16x8*)&Kc[(16 + lrow) * 64 + ((quad ^ sw7) * 8)];  \
    bf16x8 kf11 = *(const bf16x8*)&Kc[(16 + lrow) * 64 + (((4 + quad) ^ sw7) * 8)]; \
    f32x4 z0 = zl0 * LOG2E, z1 = zl1 * LOG2E;                                  \
    z0 = __builtin_amdgcn_mfma_f32_16x16x32_bf16(kf00, qf0, z0, 0, 0, 0);      \
    z0 = __builtin_amdgcn_mfma_f32_16x16x32_bf16(kf01, qf1, z0, 0, 0, 0);      \
    z1 = __builtin_amdgcn_mfma_f32_16x16x32_bf16(kf10, qf0, z1, 0, 0, 0);      \
    z1 = __builtin_amdgcn_mfma_f32_16x16x32_bf16(kf11, qf1, z1, 0, 0, 0);      \
    {                                                                          \
      float e0 = exp2f(z0[0]), e1 = exp2f(z0[1]);                              \
      float e2 = exp2f(z0[2]), e3 = exp2f(z0[3]);                              \
      lsum += (e0 + e1) + (e2 + e3);                                           \
      uint2 pp; pp.x = pk_bf16(e0, e1); pp.y = pk_bf16(e2, e3);                \
      *(uint2*)&Ph[pw + (((quad >> 1) ^ sw3) * 8) + ph4] = pp;                 \
    }                                                                          \
    {                                                                          \
      float e0 = exp2f(z1[0]), e1 = exp2f(z1[1]);                              \
      float e2 = exp2f(z1[2]), e3 = exp2f(z1[3]);                              \
      lsum += (e0 + e1) + (e2 + e3);                                           \
      uint2 pp; pp.x = pk_bf16(e0, e1); pp.y = pk_bf16(e2, e3);                \
      *(uint2*)&Ph[pw + (((2 + (quad >> 1)) ^ sw3) * 8) + ph4] = pp;           \
    }                                                                          \
    SWAIT("lgkmcnt(0)"); /* own wave-private Ph writes -> own reads */         \
    {                                                                          \
      bf16x8 pf = *(const bf16x8*)&Ph[pw + ((quad ^ sw3) * 8)];                \
      bf16x8 vf0 = *(const bf16x8*)&Vc[lrow * 32 + ((quad ^ sw3) * 8)];        \
      bf16x8 vf1 = *(const bf16x8*)&Vc[(16 + lrow) * 32 + ((quad ^ sw3) * 8)]; \
      bf16x8 vf2 = *(const bf16x8*)&Vc[(32 + lrow) * 32 + ((quad ^ sw3) * 8)]; \
      bf16x8 vf3 = *(const bf16x8*)&Vc[(48 + lrow) * 32 + ((quad ^ sw3) * 8)]; \
      o_acc0 = __builtin_amdgcn_mfma_f32_16x16x32_bf16(vf0, pf, o_acc0, 0, 0, 0); \
      o_acc1 = __builtin_amdgcn_mfma_f32_16x16x32_bf16(vf1, pf, o_acc1, 0, 0, 0); \
      o_acc2 = __builtin_amdgcn_mfma_f32_16x16x32_bf16(vf2, pf, o_acc2, 0, 0, 0); \
      o_acc3 = __builtin_amdgcn_mfma_f32_16x16x32_bf16(vf3, pf, o_acc3, 0, 0, 0); \
    }                                                                          \
  }

__global__ __launch_bounds__(512, 8)
void attn(const unsigned short* __restrict__ Qbuf,
          const unsigned short* __restrict__ Kbuf,
          const unsigned short* __restrict__ Vtbuf,
          const float* __restrict__ mask,    // raw fp32 mask
          unsigned short* __restrict__ vals) {
  const int blk = blockIdx.x;
  const int xcd = blk & 7, slot = blk >> 3;       // slot 0..127
  const int qt = xcd * 2 + (slot >> 6);           // 2 qt per XCD (mask/Q L2-local)
  const int hb = slot & 63;
  const int b = hb >> 4, h = hb & 15;
  const int tid = threadIdx.x, lane = tid & 63, w = tid >> 6;
  const int lrow = lane & 15, quad = lane >> 4;
  const int sw7 = lrow & 7, sw3 = lrow & 3;

  __shared__ __align__(16) unsigned short Ks[2][32 * 64];  // [k][d] swizzled, dbuf
  __shared__ __align__(16) unsigned short Vs[2][64 * 32];  // [d][k] swizzled, dbuf
  __shared__ __align__(16) unsigned short Ph[8 * 512];     // per-wave P 16x32

  const unsigned short* qp = Qbuf + ((size_t)(b * 16 + h) * 2048 + qt * 128) * 64;
  const unsigned short* kp = Kbuf + (size_t)(b * 16 + h) * 2048 * 64;
  const unsigned short* vp = Vtbuf + (size_t)(b * 16 + h) * 64 * 2048;
  const float* mp = mask + (size_t)(qt * 128 + w * 16) * 2048;

  // per-thread staging role: waves 0-3 stage the K tile, waves 4-7 the V tile.
  const unsigned short* sptr; int sstep;
  unsigned short *sdst0, *sdst1;
  if (w < 4) {
    int e = tid, row = e >> 3, g = (e & 7) ^ (row & 7);
    sptr = kp + row * 64 + g * 8;          // + ktn*2048 per tile
    sstep = 2048;
    sdst0 = &Ks[0][e * 8]; sdst1 = &Ks[1][e * 8];
  } else {
    int e = tid - 256, row = e >> 2, g = (e & 3) ^ (row & 3);
    sptr = vp + (size_t)row * 2048 + g * 8; // + ktn*32 per tile
    sstep = 32;
    sdst0 = &Vs[0][e * 8]; sdst1 = &Vs[1][e * 8];
  }
  const int pw = w * 512 + lrow * 32;      // per-wave P row base (shorts)
  const int ph4 = (quad & 1) * 4;          // 8B half within 16B granule

  // ---- prologue: qf direct loads, then stage(0) ----
  bf16x8 qf0 = *(const bf16x8*)(qp + (size_t)(w * 16 + lrow) * 64 + quad * 8);
  bf16x8 qf1 = *(const bf16x8*)(qp + (size_t)(w * 16 + lrow) * 64 + 32 + quad * 8);
  FENCE;
  gld_lds16(sptr, sdst0);
  FENCE;
  // tile-0 top: outstanding = [qf:2, stage:1, mask:2] -> vmcnt(2) retires qf+stage.

  f32x4 o_acc0, o_acc1, o_acc2, o_acc3;  // O^T: d = id*16+quad*4+r, q = lrow
  #pragma unroll
  for (int r = 0; r < 4; ++r) { o_acc0[r] = 0.f; o_acc1[r] = 0.f; o_acc2[r] = 0.f; o_acc3[r] = 0.f; }
  float lsum = 0.f;

  for (int tt = 0; tt < 64; tt += 2) {
    ATTN_TILE(tt, 0);
    ATTN_TILE(tt + 1, 1);
  }

  // normalize + store O^T
  float s = lsum;
  s += __shfl_xor(s, 16);
  s += __shfl_xor(s, 32);
  float inv = 1.f / s;
  unsigned short* ob = vals + (size_t)(b * 2048 + qt * 128 + w * 16 + lrow) * 1024 + h * 64;
  {
    uint2 p;
    p.x = pk_bf16(o_acc0[0] * inv, o_acc0[1] * inv);
    p.y = pk_bf16(o_acc0[2] * inv, o_acc0[3] * inv);
    *(uint2*)&ob[quad * 4] = p;
    p.x = pk_bf16(o_acc1[0] * inv, o_acc1[1] * inv);
    p.y = pk_bf16(o_acc1[2] * inv, o_acc1[3] * inv);
    *(uint2*)&ob[16 + quad * 4] = p;
    p.x = pk_bf16(o_acc2[0] * inv, o_acc2[1] * inv);
    p.y = pk_bf16(o_acc2[2] * inv, o_acc2[3] * inv);
    *(uint2*)&ob[32 + quad * 4] = p;
    p.x = pk_bf16(o_acc3[0] * inv, o_acc3[1] * inv);
    p.y = pk_bf16(o_acc3[2] * inv, o_acc3[3] * inv);
    *(uint2*)&ob[48 + quad * 4] = p;
  }
}

extern "C" void kernel_launch(void* const* d_in, const int* in_sizes, int n_in,
                              void* d_out, int out_size, void* d_ws, size_t ws_size,
                              hipStream_t stream) {
  const float* x    = (const float*)d_in[0];
  const float* y    = (const float*)d_in[1];
  const float* mask = (const float*)d_in[2];
  const float* Wkv  = (const float*)d_in[3];
  const float* bkv  = (const float*)d_in[4];
  const float* Wq   = (const float*)d_in[5];
  const float* bq   = (const float*)d_in[6];
  const float* Wo   = (const float*)d_in[7];
  const float* bo   = (const float*)d_in[8];

  char* ws = (char*)d_ws;
  unsigned short* xb    = (unsigned short*)(ws + ((size_t)0 << 20));
  unsigned short* yb    = (unsigned short*)(ws + ((size_t)16 << 20));
  unsigned short* wkvt  = (unsigned short*)(ws + ((size_t)32 << 20));
  unsigned short* wqt   = (unsigned short*)(ws + ((size_t)36 << 20));
  unsigned short* wot   = (unsigned short*)(ws + ((size_t)38 << 20));
  unsigned short* kbuf  = (unsigned short*)(ws + ((size_t)40 << 20));
  unsigned short* vtbuf = (unsigned short*)(ws + ((size_t)56 << 20));
  unsigned short* qbuf  = (unsigned short*)(ws + ((size_t)72 << 20));
  unsigned short* valsb = (unsigned short*)(ws + ((size_t)88 << 20));

  cast_xy<<<16384, 256, 0, stream>>>(x, y, xb, yb);
  transpose_cast_all<<<4096, 256, 0, stream>>>(Wkv, Wq, Wo, wkvt, wqt, wot);

  // kv = x @ Wkv + bkv -> K[b,h,s,64], Vt[b,h,64,s]
  gemm128<1><<<dim3(16, 64), 256, 0, stream>>>(xb, wkvt, bkv, kbuf, vtbuf, 8192, 2048, 1024);
  // q = y @ Wq + bq -> Q[b,h,s,64] (pre-scaled)
  gemm128<2><<<dim3(8, 64), 256, 0, stream>>>(yb, wqt, bq, qbuf, nullptr, 8192, 1024, 1024);
  // attention -> vals [b,s,1024] bf16 (mask scaled by LOG2E in-kernel)
  attn<<<1024, 512, 0, stream>>>(qbuf, kbuf, vtbuf, mask, valsb);
  // out = vals @ Wo + bo (fp32)
  gemm128<0><<<dim3(8, 64), 256, 0, stream>>>(valsb, wot, bo, (float*)d_out, nullptr, 8192, 1024, 1024);
}